// Round 6
// baseline (215.084 us; speedup 1.0000x reference)
//
#include <hip/hip_runtime.h>
#include <stdint.h>

typedef unsigned long long u64;
typedef unsigned int u32;

constexpr int Ccand = 32;   // candidates per row
constexpr int Evoc  = 512;  // vocab size
constexpr int Tgt   = 64;   // target_size

// descending bitonic sort of one f32 per lane across the 64-lane wave
__device__ __forceinline__ void sort64_desc_f32(float& a, int lane) {
    #pragma unroll
    for (int k2 = 2; k2 <= 64; k2 <<= 1) {
        #pragma unroll
        for (int j = k2 >> 1; j > 0; j >>= 1) {
            float o = __shfl_xor(a, j);
            bool lower = (lane & j) == 0;
            bool keepMax = ((lane & k2) == 0) ? lower : !lower;
            bool g = a > o;
            a = (keepMax == g) ? a : o;
        }
    }
}

// descending bitonic sort of one u64 key per lane across the wave
__device__ __forceinline__ void sort64_desc_u64(u64& a, int lane) {
    #pragma unroll
    for (int k2 = 2; k2 <= 64; k2 <<= 1) {
        #pragma unroll
        for (int j = k2 >> 1; j > 0; j >>= 1) {
            u64 o = __shfl_xor(a, j);
            bool lower = (lane & j) == 0;
            bool keepMax = ((lane & k2) == 0) ? lower : !lower;
            bool g = a > o;
            a = (keepMax == g) ? a : o;
        }
    }
}

// One wave (64 lanes) per row. Lane l owns cols {4l..4l+3} and {256+4l..+3}.
__global__ __launch_bounds__(256, 4) void cooc_expand(
    const int* __restrict__ cand_ids,
    const float* __restrict__ cand_scores,
    const float* __restrict__ cooc,
    float* __restrict__ out_ids,
    float* __restrict__ out_scores,
    int B)
{
    const int lane = threadIdx.x & 63;
    const int wid  = threadIdx.x >> 6;
    const int row  = blockIdx.x * 4 + wid;
    __shared__ u64 buf[4][512];    // per-wave survivor buffer (worst case 512)
    __shared__ u32 wmask[4][16];   // per-wave 512-bit candidate-id set
    if (row >= B) return;   // never taken (B % 4 == 0); no block barriers used

    // ---- init id-set words (lanes 0..15) ----
    if (lane < 16) wmask[wid][lane] = 0u;

    // ---- load candidates (lanes 0..31) ----
    int   my_id = -1;
    float my_s  = 0.0f;
    if (lane < Ccand) {
        my_id = cand_ids[(size_t)row * Ccand + lane];
        my_s  = cand_scores[(size_t)row * Ccand + lane];
    }

    // ---- duplicate merge, np.add.at order (ascending i, from 0.0) ----
    int   first = 64;
    float sm    = 0.0f;
    #pragma unroll
    for (int j = 0; j < Ccand; ++j) {
        int   idj = __shfl(my_id, j);   // const lane -> readlane
        float sj  = __shfl(my_s,  j);
        bool match = (idj == my_id);
        if (match && j < first) first = j;
        sm += match ? sj : 0.0f;
    }
    bool alive = (lane < Ccand) && (first == lane);
    u64 aball = __ballot(alive);
    int m = __popcll(aball);

    // ---- build 512-bit id set (order-free OR; dups idempotent) ----
    __threadfence_block();
    if (alive) atomicOr(&wmask[wid][my_id >> 5], 1u << (my_id & 31));
    __threadfence_block();

    // ---- rank via prefix-popcount of the id set ----
    u32 wword = wmask[wid][lane & 15];           // lanes 0..15 meaningful
    u32 pc = __popc(wword);
    u32 incl = pc;
    #pragma unroll
    for (int i = 1; i < 16; i <<= 1) {
        u32 t2 = __shfl_up(incl, i);
        if (lane >= i) incl += t2;
    }
    u32 scanex = incl - pc;                      // exclusive scan (lanes 0..15)
    int W = (my_id >> 5) & 15;
    u32 basew = __shfl(scanex, W);
    u32 wordw = __shfl(wword, W);
    int rk = (int)basew + __popc(wordw & ((1u << (my_id & 31)) - 1u));

    int dst = alive ? rk : ((lane < 32) ? (lane + 32) : lane);
    int sorted_id = __builtin_amdgcn_ds_permute(dst << 2, my_id);
    int sorted_sb = __builtin_amdgcn_ds_permute(dst << 2, __float_as_int(sm));

    // ---- accumulation: 4 iters x 8 ids; readlane -> SGPR base addr;
    // 16 float4 in flight per iter (fewer vmcnt stall points).
    // t>=m: s=0 (scalar select), fmaf(0,·,acc)==acc bit-exact.
    float acc[8] = {0.f,0.f,0.f,0.f,0.f,0.f,0.f,0.f};
    const int l4 = lane << 2;
    #pragma unroll 1
    for (int t = 0; t < 32; t += 8) {
        int   e[8];
        float s[8];
        #pragma unroll
        for (int u = 0; u < 8; ++u) {
            e[u] = __builtin_amdgcn_readlane(sorted_id, t + u) & 511;
            s[u] = (t + u < m) ? __int_as_float(__builtin_amdgcn_readlane(sorted_sb, t + u)) : 0.0f;
        }
        float4 A[8], Bv[8];
        #pragma unroll
        for (int u = 0; u < 8; ++u) {
            const float* rp = cooc + ((size_t)e[u] << 9);
            A[u]  = *reinterpret_cast<const float4*>(rp + l4);
            Bv[u] = *reinterpret_cast<const float4*>(rp + 256 + l4);
        }
        #pragma unroll
        for (int u = 0; u < 8; ++u) {
            acc[0] = fmaf(s[u], A[u].x,  acc[0]);
            acc[1] = fmaf(s[u], A[u].y,  acc[1]);
            acc[2] = fmaf(s[u], A[u].z,  acc[2]);
            acc[3] = fmaf(s[u], A[u].w,  acc[3]);
            acc[4] = fmaf(s[u], Bv[u].x, acc[4]);
            acc[5] = fmaf(s[u], Bv[u].y, acc[5]);
            acc[6] = fmaf(s[u], Bv[u].z, acc[6]);
            acc[7] = fmaf(s[u], Bv[u].w, acc[7]);
        }
    }

    // ---- mask flags for owned cols from the id set (2 shuffles) ----
    // low cols l4..l4+3 live in word lane>>3 at nibble (lane&7)*4;
    // high cols 256+l4.. in word 8+(lane>>3), same nibble.
    u32 wlo = __shfl(wword, lane >> 3);
    u32 whi = __shfl(wword, 8 + (lane >> 3));
    int sh = (lane & 7) << 2;
    u32 flo = (wlo >> sh) & 0xFu;
    u32 fhi = (whi >> sh) & 0xFu;

    float v[8];
    #pragma unroll
    for (int j = 0; j < 4; ++j) {
        v[j]     = ((flo >> j) & 1u) ? -1.0f : acc[j];
        v[4 + j] = ((fhi >> j) & 1u) ? -1.0f : acc[4 + j];
    }

    // ---- L32: 32nd largest of per-lane maxima; T >= L32 and every
    // top-32 element (incl. ==T ties) has v >= L32 ----
    float mx8 = v[0];
    #pragma unroll
    for (int j = 1; j < 8; ++j) mx8 = fmaxf(mx8, v[j]);
    float srt = mx8;
    sort64_desc_f32(srt, lane);
    float L32 = __int_as_float(__builtin_amdgcn_readlane(__float_as_int(srt), 31));

    // ---- survivor count + exclusive scan for LDS slots ----
    int cnt = 0;
    #pragma unroll
    for (int j = 0; j < 8; ++j) cnt += (v[j] >= L32) ? 1 : 0;
    u32 sincl = (u32)cnt;
    #pragma unroll
    for (int i = 1; i < 64; i <<= 1) {
        u32 t2 = __shfl_up(sincl, i);
        if (lane >= i) sincl += t2;
    }
    int sbase = (int)sincl - cnt;
    int S_tot = __builtin_amdgcn_readlane((int)sincl, 63);

    // ---- scatter survivor keys (valbits<<32 | 511-col): unique keys,
    // desc u64 order == np stable top-k order (value desc, col asc) ----
    int slot = sbase;
    #pragma unroll
    for (int j = 0; j < 8; ++j) {
        bool s = (v[j] >= L32);
        if (s) {
            int col = (j < 4) ? (l4 + j) : (256 + l4 + (j - 4));
            buf[wid][slot] = ((u64)__float_as_uint(v[j]) << 32) | (u32)(511 - col);
        }
        slot += s ? 1 : 0;
    }
    __threadfence_block();   // LDS visibility within the wave

    u64 k;
    if (S_tot <= 64) {
        // common path (~99.98% of rows): one 64-wide u64 bitonic sort.
        k = (lane < S_tot) ? buf[wid][lane] : 0ull;
        sort64_desc_u64(k, lane);
    } else {
        // rare exact fallback: chunked sort + merge keep-top-64
        u64 cur = (lane < S_tot) ? buf[wid][lane] : 0ull;
        sort64_desc_u64(cur, lane);
        for (int base = 64; base < S_tot; base += 64) {
            u64 nxt = (base + lane < S_tot) ? buf[wid][base + lane] : 0ull;
            sort64_desc_u64(nxt, lane);
            u64 o = __shfl_xor(nxt, 63);           // nxt[63-lane]
            cur = (cur >= o) ? cur : o;            // top-64 of 128, bitonic
            #pragma unroll
            for (int j = 32; j > 0; j >>= 1) {     // descending cleanup
                u64 p = __shfl_xor(cur, j);
                bool keepMax = (lane & j) == 0;
                bool g = cur > p;
                cur = (keepMax == g) ? cur : p;
            }
        }
        k = cur;
    }
    // lane r now holds rank-r key (r < 32 are the selected top-32)

    // ---- coalesced stores: [orig 32 | selected 32] ----
    int src = (lane >= 32) ? (lane - 32) : 0;
    u64 kk = __shfl(k, src);
    const size_t ob = (size_t)row * Tgt;
    float oid, osc;
    if (lane < Ccand) {
        oid = (float)my_id;
        osc = my_s;
    } else {
        oid = (float)(int)(511 - (u32)(kk & 511ull));
        osc = __uint_as_float((u32)(kk >> 32));
    }
    out_ids[ob + lane]    = oid;
    out_scores[ob + lane] = osc;
}

extern "C" void kernel_launch(void* const* d_in, const int* in_sizes, int n_in,
                              void* d_out, int out_size, void* d_ws, size_t ws_size,
                              hipStream_t stream) {
    const int*   ids    = (const int*)d_in[0];
    const float* scores = (const float*)d_in[1];
    const float* cooc   = (const float*)d_in[2];
    int B = in_sizes[0] / Ccand;
    float* out_ids    = (float*)d_out;
    float* out_scores = out_ids + (size_t)B * Tgt;
    int blocks = (B + 3) / 4;
    hipLaunchKernelGGL(cooc_expand, dim3(blocks), dim3(256), 0, stream,
                       ids, scores, cooc, out_ids, out_scores, B);
}